// Round 9
// baseline (622.107 us; speedup 1.0000x reference)
//
#include <hip/hip_runtime.h>

#define BATCH 32
#define CIN   256
#define CHALF 128
#define NPIX  3136   // 56*56
#define MPOOL 784    // 28*28
#define MPAD  896    // 784 padded to multiple of 32 (PV K-dim)

typedef __bf16 bf16;
typedef __bf16 bf16x2 __attribute__((ext_vector_type(2)));
typedef __bf16 bf16x4 __attribute__((ext_vector_type(4)));
typedef __bf16 bf16x8 __attribute__((ext_vector_type(8)));
typedef float  f32x4  __attribute__((ext_vector_type(4)));

// ---------------------------------------------------------------------------
// k_cast: W1,W2,W3 fp32 -> Wcat[512][256] bf16
// ---------------------------------------------------------------------------
__global__ __launch_bounds__(256) void k_cast(
    const float* __restrict__ W1, const float* __restrict__ W2,
    const float* __restrict__ W3, bf16* __restrict__ Wcat)
{
    int u = blockIdx.x * 256 + threadIdx.x;
    int o = u >> 6, k4 = (u & 63) * 4;
    const float* src = (o < 128) ? (W1 + o * 256)
                     : (o < 256) ? (W2 + (o - 128) * 256)
                                 : (W3 + (o - 256) * 256);
    float4 v = *(const float4*)(src + k4);
    bf16x4 w = { (bf16)v.x, (bf16)v.y, (bf16)v.z, (bf16)v.w };
    *(bf16x4*)(Wcat + o * 256 + k4) = w;
}

// ---------------------------------------------------------------------------
// k_conv (unchanged): MFMA 1x1 convs + fused 2x2 max+avg pool.
// ---------------------------------------------------------------------------
#define XS_STRIDE   528
#define SLAB_STRIDE 520

__global__ __launch_bounds__(512) void k_conv(
    const float* __restrict__ x, const bf16* __restrict__ Wcat,
    bf16* __restrict__ c2n, bf16* __restrict__ c1pT, bf16* __restrict__ c3p)
{
    const int h2 = blockIdx.x, b = blockIdx.y;
    const int t = threadIdx.x;
    const int lane = t & 63, wave = t >> 6;
    const int l15 = lane & 15, lg = lane >> 4;

    __shared__ __align__(16) unsigned char smem[59136];

    if (h2 == 0) {
        float4 z = {0.f, 0.f, 0.f, 0.f};
        float4* p1 = (float4*)(c1pT + (size_t)b * MPAD * CHALF + (size_t)MPOOL * CHALF);
        for (int u = t; u < 1792; u += 512) p1[u] = z;
        bf16* p3 = c3p + (size_t)b * CIN * MPAD + MPOOL;
        for (int u = t; u < 256 * 14; u += 512) {
            int c = u / 14, g = u % 14;
            *(float4*)((char*)(p3 + (size_t)c * MPAD) + g * 16) = z;
        }
    }

    {
        const float* xb = x + (size_t)b * CIN * NPIX + h2 * 112;
        float vv[14][4];
        #pragma unroll
        for (int i = 0; i < 14; ++i) {
            int u = t + i * 512;
            int c4 = u / 112, n = u - c4 * 112;
            const float* s = xb + (size_t)(c4 * 4) * NPIX + n;
            vv[i][0] = s[0];
            vv[i][1] = s[NPIX];
            vv[i][2] = s[2 * NPIX];
            vv[i][3] = s[3 * NPIX];
        }
        #pragma unroll
        for (int i = 0; i < 14; ++i) {
            int u = t + i * 512;
            int c4 = u / 112, n = u - c4 * 112;
            bf16x4 w = {(bf16)vv[i][0], (bf16)vv[i][1], (bf16)vv[i][2], (bf16)vv[i][3]};
            *(bf16x4*)(smem + n * XS_STRIDE + c4 * 8) = w;
        }
    }
    __syncthreads();

    f32x4 acc[4][7];
    #pragma unroll
    for (int fo = 0; fo < 4; ++fo)
        #pragma unroll
        for (int fn = 0; fn < 7; ++fn) {
            f32x4 zz = {0.f, 0.f, 0.f, 0.f};
            acc[fo][fn] = zz;
        }
    {
        const int o0 = wave * 64;
        const bf16* wbase = Wcat + (size_t)(o0 + l15) * 256 + lg * 8;
        const unsigned char* xsb = smem + l15 * XS_STRIDE + lg * 16;
        #pragma unroll
        for (int ks = 0; ks < 8; ++ks) {
            bf16x8 afr[4], bfr[7];
            #pragma unroll
            for (int fo = 0; fo < 4; ++fo)
                afr[fo] = *(const bf16x8*)(wbase + fo * 16 * 256 + ks * 32);
            #pragma unroll
            for (int fn = 0; fn < 7; ++fn)
                bfr[fn] = *(const bf16x8*)(xsb + fn * 16 * XS_STRIDE + ks * 64);
            #pragma unroll
            for (int fo = 0; fo < 4; ++fo)
                #pragma unroll
                for (int fn = 0; fn < 7; ++fn)
                    acc[fo][fn] = __builtin_amdgcn_mfma_f32_16x16x32_bf16(
                        afr[fo], bfr[fn], acc[fo][fn], 0, 0, 0);
        }
    }

    __syncthreads();
    if (wave < 4) {
        #pragma unroll
        for (int fo = 0; fo < 4; ++fo)
            #pragma unroll
            for (int fn = 0; fn < 7; ++fn) {
                int n = fn * 16 + l15;
                int ol = wave * 64 + fo * 16 + lg * 4;
                f32x4 a = acc[fo][fn];
                bf16x4 w = {(bf16)a[0], (bf16)a[1], (bf16)a[2], (bf16)a[3]};
                *(bf16x4*)(smem + n * SLAB_STRIDE + ol * 2) = w;
            }
    }
    __syncthreads();
    {
        bf16* dst = c1pT + (size_t)b * MPAD * CHALF + (size_t)h2 * 28 * CHALF;
        for (int u = t; u < 896; u += 512) {
            int w2 = u >> 5, o4 = (u & 31) * 4;
            bf16x4 r0 = *(bf16x4*)(smem + (2 * w2)      * SLAB_STRIDE + o4 * 2);
            bf16x4 r1 = *(bf16x4*)(smem + (2 * w2 + 1)  * SLAB_STRIDE + o4 * 2);
            bf16x4 r2 = *(bf16x4*)(smem + (56 + 2 * w2) * SLAB_STRIDE + o4 * 2);
            bf16x4 r3 = *(bf16x4*)(smem + (57 + 2 * w2) * SLAB_STRIDE + o4 * 2);
            bf16x4 o_;
            #pragma unroll
            for (int j = 0; j < 4; ++j) {
                float p0 = (float)r0[j], p1 = (float)r1[j];
                float p2 = (float)r2[j], p3 = (float)r3[j];
                float mx = fmaxf(fmaxf(p0, p1), fmaxf(p2, p3));
                float av = (p0 + p1 + p2 + p3) * 0.25f;
                o_[j] = (bf16)(mx + av);
            }
            *(bf16x4*)(dst + (size_t)w2 * CHALF + o4) = o_;
        }
    }
    {
        bf16* dst = c2n + (size_t)b * NPIX * CHALF + (size_t)h2 * 112 * CHALF;
        for (int u = t; u < 3584; u += 512) {
            int n = u >> 5, o4 = (u & 31) * 4;
            bf16x4 v = *(bf16x4*)(smem + n * SLAB_STRIDE + 256 + o4 * 2);
            *(bf16x4*)(dst + (size_t)n * CHALF + o4) = v;
        }
    }

    __syncthreads();
    if (wave >= 4) {
        #pragma unroll
        for (int fo = 0; fo < 4; ++fo)
            #pragma unroll
            for (int fn = 0; fn < 7; ++fn) {
                int n = fn * 16 + l15;
                int ol = (wave - 4) * 64 + fo * 16 + lg * 4;
                f32x4 a = acc[fo][fn];
                bf16x4 w = {(bf16)a[0], (bf16)a[1], (bf16)a[2], (bf16)a[3]};
                *(bf16x4*)(smem + n * SLAB_STRIDE + ol * 2) = w;
            }
    }
    __syncthreads();
    {
        bf16* dst = c3p + (size_t)b * CIN * MPAD + h2 * 28;
        for (int u = t; u < 3584; u += 512) {
            int c = u / 14, w2p = u - c * 14;
            bf16x2 o_;
            #pragma unroll
            for (int k = 0; k < 2; ++k) {
                int w2 = 2 * w2p + k;
                float p0 = (float)*(bf16*)(smem + (2 * w2)      * SLAB_STRIDE + c * 2);
                float p1 = (float)*(bf16*)(smem + (2 * w2 + 1)  * SLAB_STRIDE + c * 2);
                float p2 = (float)*(bf16*)(smem + (56 + 2 * w2) * SLAB_STRIDE + c * 2);
                float p3 = (float)*(bf16*)(smem + (57 + 2 * w2) * SLAB_STRIDE + c * 2);
                float mx = fmaxf(fmaxf(p0, p1), fmaxf(p2, p3));
                float av = (p0 + p1 + p2 + p3) * 0.25f;
                o_[k] = (bf16)(mx + av);
            }
            *(bf16x2*)(dst + (size_t)c * MPAD + 2 * w2p) = o_;
        }
    }
}

// ---------------------------------------------------------------------------
// k_attn v7: flash-style, ZERO block barriers, fully wave-independent.
// Each wave owns 16 n rows (block = 8 waves = 128 n). Per 32-m chunk:
//   S^T frags = mfma(c1pT, c2) -> lane n=l15 holds 8 m scores in-register ->
//   online max (2 shfl_xor across lg) + defer-max rescale (THR=8) ->
//   exp -> pack bf16 to per-wave 1.25 KB LDS bounce (80B-padded rows) ->
//   1 ds_read_b128 gives the PV B-frag -> 16 PV MFMAs into O[16] (f32).
// Epilogue: O/s_run, direct global out = g*O + x (no barriers anywhere).
// LDS = 10 KB; occupancy VGPR-limited.
// ---------------------------------------------------------------------------
__global__ __launch_bounds__(512, 2) void k_attn(
    const bf16* __restrict__ c2n,
    const bf16* __restrict__ c1pT,
    const bf16* __restrict__ c3p,
    const float* __restrict__ x,
    const float* __restrict__ gamma,
    float* __restrict__ out)
{
    const int nb = blockIdx.x, b = blockIdx.y;
    const int t = threadIdx.x;
    const int lane = t & 63, wave = t >> 6;
    const int l15 = lane & 15, lg = lane >> 4;
    const int n0 = nb * 128 + wave * 16;          // this wave's 16 n rows
    if (n0 >= NPIX) return;                       // block 24: waves 4-7 idle

    __shared__ __align__(16) unsigned char PB[8 * 1280];
    unsigned char* pb = PB + wave * 1280;         // [16 n][80 B] (32 m used)

    // c2 B-frags for this wave's n columns (held in regs)
    bf16x8 bq[4];
    {
        const bf16* c2b = c2n + ((size_t)b * NPIX + n0 + l15) * CHALF + lg * 8;
        #pragma unroll
        for (int k = 0; k < 4; ++k) bq[k] = *(const bf16x8*)(c2b + k * 32);
    }
    const bf16* c1b = c1pT + (size_t)b * MPAD * CHALF + (size_t)l15 * CHALF + lg * 8;
    const bf16* c3b = c3p  + (size_t)b * CIN * MPAD + (size_t)l15 * MPAD + lg * 8;

    f32x4 O[16];
    #pragma unroll
    for (int cf = 0; cf < 16; ++cf) {
        f32x4 z = {0.f, 0.f, 0.f, 0.f};
        O[cf] = z;
    }
    float m_run = -1e30f, s_run = 0.f;

    for (int mc = 0; mc < 25; ++mc) {
        const int m0 = mc * 32;
        const bool tail = (mc == 24);             // m 768..783 valid, 784..799 pad

        // ---- S^T: A = c1pT rows (m), B = c2 cols (n) -----------------------
        const bf16* ab = c1b + (size_t)m0 * CHALF;
        bf16x8 a0[4], a1[4];
        #pragma unroll
        for (int k = 0; k < 4; ++k) a0[k] = *(const bf16x8*)(ab + k * 32);
        if (!tail) {
            #pragma unroll
            for (int k = 0; k < 4; ++k) a1[k] = *(const bf16x8*)(ab + 16 * CHALF + k * 32);
        }
        f32x4 s0 = {0.f, 0.f, 0.f, 0.f}, s1 = {0.f, 0.f, 0.f, 0.f};
        #pragma unroll
        for (int k = 0; k < 4; ++k)
            s0 = __builtin_amdgcn_mfma_f32_16x16x32_bf16(a0[k], bq[k], s0, 0, 0, 0);
        if (!tail) {
            #pragma unroll
            for (int k = 0; k < 4; ++k)
                s1 = __builtin_amdgcn_mfma_f32_16x16x32_bf16(a1[k], bq[k], s1, 0, 0, 0);
        }

        // ---- online softmax (per-n: lanes sharing l15 reduce across lg) ----
        float pm = fmaxf(fmaxf(s0[0], s0[1]), fmaxf(s0[2], s0[3]));
        if (!tail) pm = fmaxf(pm, fmaxf(fmaxf(s1[0], s1[1]), fmaxf(s1[2], s1[3])));
        pm = fmaxf(pm, __shfl_xor(pm, 16));
        pm = fmaxf(pm, __shfl_xor(pm, 32));
        if (__any(pm > m_run + 8.f)) {            // T13 defer-max
            float mn = fmaxf(m_run, pm);
            float sc = __expf(m_run - mn);
            s_run *= sc;
            #pragma unroll
            for (int cf = 0; cf < 16; ++cf) {
                O[cf][0] *= sc; O[cf][1] *= sc; O[cf][2] *= sc; O[cf][3] *= sc;
            }
            m_run = mn;
        }
        float e0[4], e1[4];
        float cs = 0.f;
        #pragma unroll
        for (int r = 0; r < 4; ++r) { e0[r] = __expf(s0[r] - m_run); cs += e0[r]; }
        if (!tail) {
            #pragma unroll
            for (int r = 0; r < 4; ++r) { e1[r] = __expf(s1[r] - m_run); cs += e1[r]; }
        } else {
            #pragma unroll
            for (int r = 0; r < 4; ++r) e1[r] = 0.f;
        }
        cs += __shfl_xor(cs, 16);
        cs += __shfl_xor(cs, 32);
        s_run += cs;

        // ---- pack P chunk to LDS: row n=l15, byte = m*2 (m = f*16+lg*4+r) --
        {
            unsigned char* pw = pb + l15 * 80 + lg * 8;
            *(bf16x2*)(pw)      = bf16x2{ (bf16)e0[0], (bf16)e0[1] };
            *(bf16x2*)(pw + 4)  = bf16x2{ (bf16)e0[2], (bf16)e0[3] };
            *(bf16x2*)(pw + 32) = bf16x2{ (bf16)e1[0], (bf16)e1[1] };
            *(bf16x2*)(pw + 36) = bf16x2{ (bf16)e1[2], (bf16)e1[3] };
        }
        // PV B-frag: lane n=l15, k-slice m = lg*8..+7 (16B contiguous)
        bf16x8 pfrag = *(const bf16x8*)(pb + l15 * 80 + lg * 16);

        // ---- PV: A = V rows (c), accumulate O[cf] --------------------------
        const bf16* vb = c3b + m0;
        #pragma unroll
        for (int cf = 0; cf < 16; ++cf) {
            bf16x8 vf = *(const bf16x8*)(vb + (size_t)cf * 16 * MPAD);
            O[cf] = __builtin_amdgcn_mfma_f32_16x16x32_bf16(vf, pfrag, O[cf], 0, 0, 0);
        }
    }

    // ---- epilogue: normalize, out = g*refined + x (direct, coalesced 64B) --
    const float ri = 1.f / s_run;
    const float g = gamma[0];
    const float* xb = x + (size_t)b * CIN * NPIX + n0 + l15;
    float* ob = out + (size_t)b * CIN * NPIX + n0 + l15;
    #pragma unroll
    for (int cf = 0; cf < 16; ++cf) {
        #pragma unroll
        for (int r = 0; r < 4; ++r) {
            size_t off = (size_t)(cf * 16 + lg * 4 + r) * NPIX;
            ob[off] = g * O[cf][r] * ri + xb[off];
        }
    }
}

extern "C" void kernel_launch(void* const* d_in, const int* in_sizes, int n_in,
                              void* d_out, int out_size, void* d_ws, size_t ws_size,
                              hipStream_t stream) {
    const float* x     = (const float*)d_in[0];
    const float* W1    = (const float*)d_in[1];
    const float* W2    = (const float*)d_in[2];
    const float* W3    = (const float*)d_in[3];
    const float* gamma = (const float*)d_in[4];
    float* out = (float*)d_out;

    bf16* ws   = (bf16*)d_ws;
    bf16* Wcat = ws;                                       // 512*256
    bf16* c2n  = Wcat + (size_t)512 * 256;                 // 32*3136*128
    bf16* c1pT = c2n + (size_t)BATCH * NPIX * CHALF;       // 32*896*128
    bf16* c3p  = c1pT + (size_t)BATCH * MPAD * CHALF;      // 32*256*896

    k_cast<<<128, 256, 0, stream>>>(W1, W2, W3, Wcat);
    k_conv<<<dim3(28, BATCH), 512, 0, stream>>>(x, Wcat, c2n, c1pT, c3p);
    k_attn<<<dim3(25, BATCH), 512, 0, stream>>>(c2n, c1pT, c3p, x, gamma, out);
}

// Round 10
// 431.390 us; speedup vs baseline: 1.4421x; 1.4421x over previous
//
#include <hip/hip_runtime.h>

#define BATCH 32
#define CIN   256
#define CHALF 128
#define NPIX  3136   // 56*56
#define MPOOL 784    // 28*28
#define MPAD  896    // c1pT/c3p m-padding (from k_conv)
#define MP2   800    // P row stride (784 + 16 pad), 25 K-chunks of 32

typedef __bf16 bf16;
typedef __bf16 bf16x2 __attribute__((ext_vector_type(2)));
typedef __bf16 bf16x4 __attribute__((ext_vector_type(4)));
typedef __bf16 bf16x8 __attribute__((ext_vector_type(8)));
typedef float  f32x4  __attribute__((ext_vector_type(4)));

// ---------------------------------------------------------------------------
// k_cast: W1,W2,W3 fp32 -> Wcat[512][256] bf16
// ---------------------------------------------------------------------------
__global__ __launch_bounds__(256) void k_cast(
    const float* __restrict__ W1, const float* __restrict__ W2,
    const float* __restrict__ W3, bf16* __restrict__ Wcat)
{
    int u = blockIdx.x * 256 + threadIdx.x;
    int o = u >> 6, k4 = (u & 63) * 4;
    const float* src = (o < 128) ? (W1 + o * 256)
                     : (o < 256) ? (W2 + (o - 128) * 256)
                                 : (W3 + (o - 256) * 256);
    float4 v = *(const float4*)(src + k4);
    bf16x4 w = { (bf16)v.x, (bf16)v.y, (bf16)v.z, (bf16)v.w };
    *(bf16x4*)(Wcat + o * 256 + k4) = w;
}

// ---------------------------------------------------------------------------
// k_conv (unchanged): MFMA 1x1 convs + fused 2x2 max+avg pool.
// ---------------------------------------------------------------------------
#define XS_STRIDE   528
#define SLAB_STRIDE 520

__global__ __launch_bounds__(512) void k_conv(
    const float* __restrict__ x, const bf16* __restrict__ Wcat,
    bf16* __restrict__ c2n, bf16* __restrict__ c1pT, bf16* __restrict__ c3p)
{
    const int h2 = blockIdx.x, b = blockIdx.y;
    const int t = threadIdx.x;
    const int lane = t & 63, wave = t >> 6;
    const int l15 = lane & 15, lg = lane >> 4;

    __shared__ __align__(16) unsigned char smem[59136];

    if (h2 == 0) {
        float4 z = {0.f, 0.f, 0.f, 0.f};
        float4* p1 = (float4*)(c1pT + (size_t)b * MPAD * CHALF + (size_t)MPOOL * CHALF);
        for (int u = t; u < 1792; u += 512) p1[u] = z;
        bf16* p3 = c3p + (size_t)b * CIN * MPAD + MPOOL;
        for (int u = t; u < 256 * 14; u += 512) {
            int c = u / 14, g = u % 14;
            *(float4*)((char*)(p3 + (size_t)c * MPAD) + g * 16) = z;
        }
    }

    {
        const float* xb = x + (size_t)b * CIN * NPIX + h2 * 112;
        float vv[14][4];
        #pragma unroll
        for (int i = 0; i < 14; ++i) {
            int u = t + i * 512;
            int c4 = u / 112, n = u - c4 * 112;
            const float* s = xb + (size_t)(c4 * 4) * NPIX + n;
            vv[i][0] = s[0];
            vv[i][1] = s[NPIX];
            vv[i][2] = s[2 * NPIX];
            vv[i][3] = s[3 * NPIX];
        }
        #pragma unroll
        for (int i = 0; i < 14; ++i) {
            int u = t + i * 512;
            int c4 = u / 112, n = u - c4 * 112;
            bf16x4 w = {(bf16)vv[i][0], (bf16)vv[i][1], (bf16)vv[i][2], (bf16)vv[i][3]};
            *(bf16x4*)(smem + n * XS_STRIDE + c4 * 8) = w;
        }
    }
    __syncthreads();

    f32x4 acc[4][7];
    #pragma unroll
    for (int fo = 0; fo < 4; ++fo)
        #pragma unroll
        for (int fn = 0; fn < 7; ++fn) {
            f32x4 zz = {0.f, 0.f, 0.f, 0.f};
            acc[fo][fn] = zz;
        }
    {
        const int o0 = wave * 64;
        const bf16* wbase = Wcat + (size_t)(o0 + l15) * 256 + lg * 8;
        const unsigned char* xsb = smem + l15 * XS_STRIDE + lg * 16;
        #pragma unroll
        for (int ks = 0; ks < 8; ++ks) {
            bf16x8 afr[4], bfr[7];
            #pragma unroll
            for (int fo = 0; fo < 4; ++fo)
                afr[fo] = *(const bf16x8*)(wbase + fo * 16 * 256 + ks * 32);
            #pragma unroll
            for (int fn = 0; fn < 7; ++fn)
                bfr[fn] = *(const bf16x8*)(xsb + fn * 16 * XS_STRIDE + ks * 64);
            #pragma unroll
            for (int fo = 0; fo < 4; ++fo)
                #pragma unroll
                for (int fn = 0; fn < 7; ++fn)
                    acc[fo][fn] = __builtin_amdgcn_mfma_f32_16x16x32_bf16(
                        afr[fo], bfr[fn], acc[fo][fn], 0, 0, 0);
        }
    }

    __syncthreads();
    if (wave < 4) {
        #pragma unroll
        for (int fo = 0; fo < 4; ++fo)
            #pragma unroll
            for (int fn = 0; fn < 7; ++fn) {
                int n = fn * 16 + l15;
                int ol = wave * 64 + fo * 16 + lg * 4;
                f32x4 a = acc[fo][fn];
                bf16x4 w = {(bf16)a[0], (bf16)a[1], (bf16)a[2], (bf16)a[3]};
                *(bf16x4*)(smem + n * SLAB_STRIDE + ol * 2) = w;
            }
    }
    __syncthreads();
    {
        bf16* dst = c1pT + (size_t)b * MPAD * CHALF + (size_t)h2 * 28 * CHALF;
        for (int u = t; u < 896; u += 512) {
            int w2 = u >> 5, o4 = (u & 31) * 4;
            bf16x4 r0 = *(bf16x4*)(smem + (2 * w2)      * SLAB_STRIDE + o4 * 2);
            bf16x4 r1 = *(bf16x4*)(smem + (2 * w2 + 1)  * SLAB_STRIDE + o4 * 2);
            bf16x4 r2 = *(bf16x4*)(smem + (56 + 2 * w2) * SLAB_STRIDE + o4 * 2);
            bf16x4 r3 = *(bf16x4*)(smem + (57 + 2 * w2) * SLAB_STRIDE + o4 * 2);
            bf16x4 o_;
            #pragma unroll
            for (int j = 0; j < 4; ++j) {
                float p0 = (float)r0[j], p1 = (float)r1[j];
                float p2 = (float)r2[j], p3 = (float)r3[j];
                float mx = fmaxf(fmaxf(p0, p1), fmaxf(p2, p3));
                float av = (p0 + p1 + p2 + p3) * 0.25f;
                o_[j] = (bf16)(mx + av);
            }
            *(bf16x4*)(dst + (size_t)w2 * CHALF + o4) = o_;
        }
    }
    {
        bf16* dst = c2n + (size_t)b * NPIX * CHALF + (size_t)h2 * 112 * CHALF;
        for (int u = t; u < 3584; u += 512) {
            int n = u >> 5, o4 = (u & 31) * 4;
            bf16x4 v = *(bf16x4*)(smem + n * SLAB_STRIDE + 256 + o4 * 2);
            *(bf16x4*)(dst + (size_t)n * CHALF + o4) = v;
        }
    }

    __syncthreads();
    if (wave >= 4) {
        #pragma unroll
        for (int fo = 0; fo < 4; ++fo)
            #pragma unroll
            for (int fn = 0; fn < 7; ++fn) {
                int n = fn * 16 + l15;
                int ol = (wave - 4) * 64 + fo * 16 + lg * 4;
                f32x4 a = acc[fo][fn];
                bf16x4 w = {(bf16)a[0], (bf16)a[1], (bf16)a[2], (bf16)a[3]};
                *(bf16x4*)(smem + n * SLAB_STRIDE + ol * 2) = w;
            }
    }
    __syncthreads();
    {
        bf16* dst = c3p + (size_t)b * CIN * MPAD + h2 * 28;
        for (int u = t; u < 3584; u += 512) {
            int c = u / 14, w2p = u - c * 14;
            bf16x2 o_;
            #pragma unroll
            for (int k = 0; k < 2; ++k) {
                int w2 = 2 * w2p + k;
                float p0 = (float)*(bf16*)(smem + (2 * w2)      * SLAB_STRIDE + c * 2);
                float p1 = (float)*(bf16*)(smem + (2 * w2 + 1)  * SLAB_STRIDE + c * 2);
                float p2 = (float)*(bf16*)(smem + (56 + 2 * w2) * SLAB_STRIDE + c * 2);
                float p3 = (float)*(bf16*)(smem + (57 + 2 * w2) * SLAB_STRIDE + c * 2);
                float mx = fmaxf(fmaxf(p0, p1), fmaxf(p2, p3));
                float av = (p0 + p1 + p2 + p3) * 0.25f;
                o_[k] = (bf16)(mx + av);
            }
            *(bf16x2*)(dst + (size_t)c * MPAD + 2 * w2p) = o_;
        }
    }
}

// ---------------------------------------------------------------------------
// k_score: swapped-operand S^T + in-register softmax (v5's proven math),
// P written normalized bf16 to ws via a coalescing LDS bounce.
// grid (98, 8 batches of the ring); block 512; nt=32.
// Waves: p = wave&1 (16-row n-frag), h = wave>>1 (224-m quarter).
// LDS: bounce [32 n][1808 B] (m<800 used) + EX 1 KB = 58.9 KB -> 2 blocks/CU.
// ---------------------------------------------------------------------------
__global__ __launch_bounds__(512) void k_score(
    const bf16* __restrict__ c2n, const bf16* __restrict__ c1pT,
    bf16* __restrict__ P, int b_base)
{
    const int nb = blockIdx.x, b8 = blockIdx.y;
    const int b = b_base + b8;
    const int n0 = nb * 32;
    const int t = threadIdx.x;
    const int lane = t & 63, wave = t >> 6;
    const int l15 = lane & 15, lg = lane >> 4;
    const int p = wave & 1, h = wave >> 1;

    __shared__ __align__(16) unsigned char smem[58880];
    float* EX = (float*)(smem + 57856);           // [2][8][16]

    // c2 fragments (B operand, n side)
    bf16x8 bq[4];
    {
        const bf16* c2b = c2n + ((size_t)b * NPIX + n0 + p * 16 + l15) * CHALF + lg * 8;
        #pragma unroll
        for (int k = 0; k < 4; ++k)
            bq[k] = *(const bf16x8*)(c2b + k * 32);
    }
    f32x4 sacc[14];
    {
        const bf16* c1b = c1pT + ((size_t)b * MPAD + h * 224 + l15) * CHALF + lg * 8;
        #pragma unroll
        for (int mf = 0; mf < 14; ++mf) {
            f32x4 z = {0.f, 0.f, 0.f, 0.f};
            sacc[mf] = z;
            bf16x8 af[4];
            #pragma unroll
            for (int k = 0; k < 4; ++k)
                af[k] = *(const bf16x8*)(c1b + (size_t)mf * 16 * CHALF + k * 32);
            #pragma unroll
            for (int k = 0; k < 4; ++k)
                sacc[mf] = __builtin_amdgcn_mfma_f32_16x16x32_bf16(af[k], bq[k], sacc[mf], 0, 0, 0);
        }
    }

    // in-register softmax (valid: h<3 all, h==3 -> mf<7)
    float mx = -1e30f;
    #pragma unroll
    for (int mf = 0; mf < 14; ++mf) {
        if (h < 3 || mf < 7) {
            mx = fmaxf(mx, fmaxf(fmaxf(sacc[mf][0], sacc[mf][1]),
                                 fmaxf(sacc[mf][2], sacc[mf][3])));
        }
    }
    mx = fmaxf(mx, __shfl_xor(mx, 16));
    mx = fmaxf(mx, __shfl_xor(mx, 32));
    if (lane < 16) EX[wave * 16 + l15] = mx;
    __syncthreads();
    {
        float m0 = EX[p * 16 + l15],        m1 = EX[(2 + p) * 16 + l15];
        float m2 = EX[(4 + p) * 16 + l15],  m3 = EX[(6 + p) * 16 + l15];
        mx = fmaxf(fmaxf(m0, m1), fmaxf(m2, m3));
    }
    float s = 0.f;
    #pragma unroll
    for (int mf = 0; mf < 14; ++mf) {
        if (h < 3 || mf < 7) {
            #pragma unroll
            for (int r = 0; r < 4; ++r) {
                float e = __expf(sacc[mf][r] - mx);
                sacc[mf][r] = e;
                s += e;
            }
        }
    }
    s += __shfl_xor(s, 16);
    s += __shfl_xor(s, 32);
    if (lane < 16) EX[128 + wave * 16 + l15] = s;
    __syncthreads();
    {
        float s0 = EX[128 + p * 16 + l15],       s1 = EX[128 + (2 + p) * 16 + l15];
        float s2 = EX[128 + (4 + p) * 16 + l15], s3 = EX[128 + (6 + p) * 16 + l15];
        s = (s0 + s1) + (s2 + s3);
    }
    const float ri = 1.f / s;

    // pack normalized P into bounce: row n-local, byte m*2
    {
        const unsigned rowb = (unsigned)((p * 16 + l15) * 1808);
        #pragma unroll
        for (int mf = 0; mf < 14; ++mf) {
            bf16x4 w;
            if (h < 3 || mf < 7) {
                w = bf16x4{ (bf16)(sacc[mf][0] * ri), (bf16)(sacc[mf][1] * ri),
                            (bf16)(sacc[mf][2] * ri), (bf16)(sacc[mf][3] * ri) };
            } else {
                w = bf16x4{ (bf16)0.f, (bf16)0.f, (bf16)0.f, (bf16)0.f };
            }
            *(bf16x4*)(smem + rowb + (unsigned)(h * 448 + mf * 32 + lg * 8)) = w;
        }
    }
    __syncthreads();

    // cooperative coalesced write: 32 rows x 1600 B (m<800) = 3200 x 16B segs
    {
        unsigned char* Pb = (unsigned char*)(P + ((size_t)b8 * NPIX + n0) * MP2);
        #pragma unroll
        for (int i = 0; i < 7; ++i) {
            int seg = t + i * 512;
            if (seg < 3200) {
                int row = seg / 100, sg = seg - row * 100;
                *(uint4*)(Pb + (size_t)row * 1600 + sg * 16) =
                    *(const uint4*)(smem + row * 1808 + sg * 16);
            }
        }
    }
}

// ---------------------------------------------------------------------------
// k_pv: pure GEMM refined[c][n] = sum_m V[c][m] * P[n][m], K=800 (25 chunks),
// v3-style double-buffered pre-swizzled staging of BOTH operands.
// grid (49, 8); block 512; waves: cq = wave>>1 (64-c), nh = wave&1 (32-n).
// LDS: 2 x (A 16 KB + B 4 KB) = 40 KB, overlaid by R [64][257] f32 (66 KB).
// Epilogue: out = gamma*refined + x.
// ---------------------------------------------------------------------------
__global__ __launch_bounds__(512) void k_pv(
    const bf16* __restrict__ c3p, const bf16* __restrict__ P,
    const float* __restrict__ x, const float* __restrict__ gamma,
    float* __restrict__ out, int b_base)
{
    const int nb = blockIdx.x, b8 = blockIdx.y;
    const int b = b_base + b8;
    const int n0 = nb * 64;
    const int t = threadIdx.x;
    const int lane = t & 63, wave = t >> 6;
    const int l15 = lane & 15, lg = lane >> 4;
    const int cq = wave >> 1, nh = wave & 1;

    __shared__ __align__(16) unsigned char smem[65792];

    const bf16* c3b = c3p + (size_t)b * CIN * MPAD;
    const bf16* Pb  = P + ((size_t)b8 * NPIX + n0) * MP2;

    // staging source addresses (pre-swizzled globals, linear LDS — rule #21)
    const int sc = t >> 1, shf = t & 1;
    const bf16* as0 = c3b + (size_t)sc * MPAD + (((shf * 2)     ^ (sc & 3)) * 8);
    const bf16* as1 = c3b + (size_t)sc * MPAD + (((shf * 2 + 1) ^ (sc & 3)) * 8);
    const int sn = t >> 3, sq = t & 7;
    const bf16* bs  = Pb + (size_t)sn * MP2 + (((sq >> 1) ^ (sn & 3)) * 8) + (sq & 1) * 4;

    uint4 xa0, xa1; uint2 xbv;        // set X (even chunks)
    uint4 ya0, ya1; uint2 ybv;        // set Y (odd chunks)

    #define LDX(ks) { xa0 = *(const uint4*)(as0 + (ks)*32); \
                      xa1 = *(const uint4*)(as1 + (ks)*32); \
                      xbv = *(const uint2*)(bs  + (ks)*32); }
    #define LDY(ks) { ya0 = *(const uint4*)(as0 + (ks)*32); \
                      ya1 = *(const uint4*)(as1 + (ks)*32); \
                      ybv = *(const uint2*)(bs  + (ks)*32); }
    #define WRX(bi) { unsigned char* _b = smem + (bi)*20480; \
                      *(uint4*)(_b + t*32) = xa0; *(uint4*)(_b + t*32 + 16) = xa1; \
                      *(uint2*)(_b + 16384 + t*8) = xbv; }
    #define WRY(bi) { unsigned char* _b = smem + (bi)*20480; \
                      *(uint4*)(_b + t*32) = ya0; *(uint4*)(_b + t*32 + 16) = ya1; \
                      *(uint2*)(_b + 16384 + t*8) = ybv; }

    LDX(0); WRX(0);
    LDY(1);

    f32x4 acc[4][2];
    #pragma unroll
    for (int cf = 0; cf < 4; ++cf)
        #pragma unroll
        for (int nf = 0; nf < 2; ++nf) {
            f32x4 z = {0.f, 0.f, 0.f, 0.f};
            acc[cf][nf] = z;
        }
    __syncthreads();

    for (int ks = 0; ks < 25; ++ks) {
        const int cur = ks & 1;
        if (ks + 1 < 25) {
            if (cur == 0) { WRY(1); } else { WRX(0); }
        }
        if (ks + 2 < 25) {
            if (cur == 0) { LDX(ks + 2); } else { LDY(ks + 2); }
        }
        {
            const unsigned char* Ab = smem + cur * 20480;
            const unsigned char* Bb = Ab + 16384;
            bf16x8 vf[4], pf[2];
            #pragma unroll
            for (int cf = 0; cf < 4; ++cf) {
                int c = cq * 64 + cf * 16 + l15;
                vf[cf] = *(const bf16x8*)(Ab + c * 64 + ((lg ^ (c & 3)) * 16));
            }
            #pragma unroll
            for (int nf = 0; nf < 2; ++nf) {
                int n = nh * 32 + nf * 16 + l15;
                pf[nf] = *(const bf16x8*)(Bb + n * 64 + ((lg ^ (n & 3)) * 16));
            }
            #pragma unroll
            for (int cf = 0; cf < 4; ++cf)
                #pragma unroll
                for (int nf = 0; nf < 2; ++nf)
                    acc[cf][nf] = __builtin_amdgcn_mfma_f32_16x16x32_bf16(
                        vf[cf], pf[nf], acc[cf][nf], 0, 0, 0);
        }
        __syncthreads();
    }

    // epilogue: R[n][c] transpose -> coalesced out = g*refined + x
    float* R = (float*)smem;   // [64][257]
    #pragma unroll
    for (int cf = 0; cf < 4; ++cf)
        #pragma unroll
        for (int nf = 0; nf < 2; ++nf) {
            int c = cq * 64 + cf * 16 + lg * 4;
            int n = nh * 32 + nf * 16 + l15;
            #pragma unroll
            for (int r = 0; r < 4; ++r)
                R[n * 257 + c + r] = acc[cf][nf][r];
        }
    __syncthreads();
    const float g = gamma[0];
    const float* xp = x + (size_t)b * CIN * NPIX + n0;
    float* op = out + (size_t)b * CIN * NPIX + n0;
    #pragma unroll 4
    for (int i = 0; i < 32; ++i) {
        int idx = t + i * 512;                  // 256 c x 64 n
        int c = idx >> 6, nn = idx & 63;
        size_t off = (size_t)c * NPIX + nn;
        op[off] = g * R[nn * 257 + c] + xp[off];
    }
    #undef LDX
    #undef LDY
    #undef WRX
    #undef WRY
}

extern "C" void kernel_launch(void* const* d_in, const int* in_sizes, int n_in,
                              void* d_out, int out_size, void* d_ws, size_t ws_size,
                              hipStream_t stream) {
    const float* x     = (const float*)d_in[0];
    const float* W1    = (const float*)d_in[1];
    const float* W2    = (const float*)d_in[2];
    const float* W3    = (const float*)d_in[3];
    const float* gamma = (const float*)d_in[4];
    float* out = (float*)d_out;

    bf16* ws   = (bf16*)d_ws;
    bf16* Wcat = ws;                                       // 512*256
    bf16* c2n  = Wcat + (size_t)512 * 256;                 // 32*3136*128
    bf16* c1pT = c2n + (size_t)BATCH * NPIX * CHALF;       // 32*896*128
    bf16* c3p  = c1pT + (size_t)BATCH * MPAD * CHALF;      // 32*256*896
    bf16* Prb  = c3p + (size_t)BATCH * CIN * MPAD;         // 8*3136*800 ring

    k_cast<<<128, 256, 0, stream>>>(W1, W2, W3, Wcat);
    k_conv<<<dim3(28, BATCH), 512, 0, stream>>>(x, Wcat, c2n, c1pT, c3p);
    for (int g = 0; g < 4; ++g) {
        k_score<<<dim3(98, 8), 512, 0, stream>>>(c2n, c1pT, Prb, g * 8);
        k_pv<<<dim3(49, 8), 512, 0, stream>>>(c3p, Prb, x, gamma, out, g * 8);
    }
}

// Round 11
// 245.007 us; speedup vs baseline: 2.5391x; 1.7607x over previous
//
#include <hip/hip_runtime.h>

#define BATCH 32
#define CIN   256
#define CHALF 128
#define NPIX  3136   // 56*56
#define MPOOL 784    // 28*28
#define MPAD  896    // 784 padded to multiple of 32

typedef __bf16 bf16;
typedef __bf16 bf16x2 __attribute__((ext_vector_type(2)));
typedef __bf16 bf16x4 __attribute__((ext_vector_type(4)));
typedef __bf16 bf16x8 __attribute__((ext_vector_type(8)));
typedef float  f32x4  __attribute__((ext_vector_type(4)));

// ---------------------------------------------------------------------------
// k_cast: W1,W2,W3 fp32 -> Wcat[512][256] bf16
// ---------------------------------------------------------------------------
__global__ __launch_bounds__(256) void k_cast(
    const float* __restrict__ W1, const float* __restrict__ W2,
    const float* __restrict__ W3, bf16* __restrict__ Wcat)
{
    int u = blockIdx.x * 256 + threadIdx.x;
    int o = u >> 6, k4 = (u & 63) * 4;
    const float* src = (o < 128) ? (W1 + o * 256)
                     : (o < 256) ? (W2 + (o - 128) * 256)
                                 : (W3 + (o - 256) * 256);
    float4 v = *(const float4*)(src + k4);
    bf16x4 w = { (bf16)v.x, (bf16)v.y, (bf16)v.z, (bf16)v.w };
    *(bf16x4*)(Wcat + o * 256 + k4) = w;
}

// ---------------------------------------------------------------------------
// k_conv (unchanged): MFMA 1x1 convs + fused 2x2 max+avg pool.
// ---------------------------------------------------------------------------
#define XS_STRIDE   528
#define SLAB_STRIDE 520

__global__ __launch_bounds__(512) void k_conv(
    const float* __restrict__ x, const bf16* __restrict__ Wcat,
    bf16* __restrict__ c2n, bf16* __restrict__ c1pT, bf16* __restrict__ c3p)
{
    const int h2 = blockIdx.x, b = blockIdx.y;
    const int t = threadIdx.x;
    const int lane = t & 63, wave = t >> 6;
    const int l15 = lane & 15, lg = lane >> 4;

    __shared__ __align__(16) unsigned char smem[59136];

    if (h2 == 0) {
        float4 z = {0.f, 0.f, 0.f, 0.f};
        float4* p1 = (float4*)(c1pT + (size_t)b * MPAD * CHALF + (size_t)MPOOL * CHALF);
        for (int u = t; u < 1792; u += 512) p1[u] = z;
        bf16* p3 = c3p + (size_t)b * CIN * MPAD + MPOOL;
        for (int u = t; u < 256 * 14; u += 512) {
            int c = u / 14, g = u % 14;
            *(float4*)((char*)(p3 + (size_t)c * MPAD) + g * 16) = z;
        }
    }

    {
        const float* xb = x + (size_t)b * CIN * NPIX + h2 * 112;
        float vv[14][4];
        #pragma unroll
        for (int i = 0; i < 14; ++i) {
            int u = t + i * 512;
            int c4 = u / 112, n = u - c4 * 112;
            const float* s = xb + (size_t)(c4 * 4) * NPIX + n;
            vv[i][0] = s[0];
            vv[i][1] = s[NPIX];
            vv[i][2] = s[2 * NPIX];
            vv[i][3] = s[3 * NPIX];
        }
        #pragma unroll
        for (int i = 0; i < 14; ++i) {
            int u = t + i * 512;
            int c4 = u / 112, n = u - c4 * 112;
            bf16x4 w = {(bf16)vv[i][0], (bf16)vv[i][1], (bf16)vv[i][2], (bf16)vv[i][3]};
            *(bf16x4*)(smem + n * XS_STRIDE + c4 * 8) = w;
        }
    }
    __syncthreads();

    f32x4 acc[4][7];
    #pragma unroll
    for (int fo = 0; fo < 4; ++fo)
        #pragma unroll
        for (int fn = 0; fn < 7; ++fn) {
            f32x4 zz = {0.f, 0.f, 0.f, 0.f};
            acc[fo][fn] = zz;
        }
    {
        const int o0 = wave * 64;
        const bf16* wbase = Wcat + (size_t)(o0 + l15) * 256 + lg * 8;
        const unsigned char* xsb = smem + l15 * XS_STRIDE + lg * 16;
        #pragma unroll
        for (int ks = 0; ks < 8; ++ks) {
            bf16x8 afr[4], bfr[7];
            #pragma unroll
            for (int fo = 0; fo < 4; ++fo)
                afr[fo] = *(const bf16x8*)(wbase + fo * 16 * 256 + ks * 32);
            #pragma unroll
            for (int fn = 0; fn < 7; ++fn)
                bfr[fn] = *(const bf16x8*)(xsb + fn * 16 * XS_STRIDE + ks * 64);
            #pragma unroll
            for (int fo = 0; fo < 4; ++fo)
                #pragma unroll
                for (int fn = 0; fn < 7; ++fn)
                    acc[fo][fn] = __builtin_amdgcn_mfma_f32_16x16x32_bf16(
                        afr[fo], bfr[fn], acc[fo][fn], 0, 0, 0);
        }
    }

    __syncthreads();
    if (wave < 4) {
        #pragma unroll
        for (int fo = 0; fo < 4; ++fo)
            #pragma unroll
            for (int fn = 0; fn < 7; ++fn) {
                int n = fn * 16 + l15;
                int ol = wave * 64 + fo * 16 + lg * 4;
                f32x4 a = acc[fo][fn];
                bf16x4 w = {(bf16)a[0], (bf16)a[1], (bf16)a[2], (bf16)a[3]};
                *(bf16x4*)(smem + n * SLAB_STRIDE + ol * 2) = w;
            }
    }
    __syncthreads();
    {
        bf16* dst = c1pT + (size_t)b * MPAD * CHALF + (size_t)h2 * 28 * CHALF;
        for (int u = t; u < 896; u += 512) {
            int w2 = u >> 5, o4 = (u & 31) * 4;
            bf16x4 r0 = *(bf16x4*)(smem + (2 * w2)      * SLAB_STRIDE + o4 * 2);
            bf16x4 r1 = *(bf16x4*)(smem + (2 * w2 + 1)  * SLAB_STRIDE + o4 * 2);
            bf16x4 r2 = *(bf16x4*)(smem + (56 + 2 * w2) * SLAB_STRIDE + o4 * 2);
            bf16x4 r3 = *(bf16x4*)(smem + (57 + 2 * w2) * SLAB_STRIDE + o4 * 2);
            bf16x4 o_;
            #pragma unroll
            for (int j = 0; j < 4; ++j) {
                float p0 = (float)r0[j], p1 = (float)r1[j];
                float p2 = (float)r2[j], p3 = (float)r3[j];
                float mx = fmaxf(fmaxf(p0, p1), fmaxf(p2, p3));
                float av = (p0 + p1 + p2 + p3) * 0.25f;
                o_[j] = (bf16)(mx + av);
            }
            *(bf16x4*)(dst + (size_t)w2 * CHALF + o4) = o_;
        }
    }
    {
        bf16* dst = c2n + (size_t)b * NPIX * CHALF + (size_t)h2 * 112 * CHALF;
        for (int u = t; u < 3584; u += 512) {
            int n = u >> 5, o4 = (u & 31) * 4;
            bf16x4 v = *(bf16x4*)(smem + n * SLAB_STRIDE + 256 + o4 * 2);
            *(bf16x4*)(dst + (size_t)n * CHALF + o4) = v;
        }
    }

    __syncthreads();
    if (wave >= 4) {
        #pragma unroll
        for (int fo = 0; fo < 4; ++fo)
            #pragma unroll
            for (int fn = 0; fn < 7; ++fn) {
                int n = fn * 16 + l15;
                int ol = (wave - 4) * 64 + fo * 16 + lg * 4;
                f32x4 a = acc[fo][fn];
                bf16x4 w = {(bf16)a[0], (bf16)a[1], (bf16)a[2], (bf16)a[3]};
                *(bf16x4*)(smem + n * SLAB_STRIDE + ol * 2) = w;
            }
    }
    __syncthreads();
    {
        bf16* dst = c3p + (size_t)b * CIN * MPAD + h2 * 28;
        for (int u = t; u < 3584; u += 512) {
            int c = u / 14, w2p = u - c * 14;
            bf16x2 o_;
            #pragma unroll
            for (int k = 0; k < 2; ++k) {
                int w2 = 2 * w2p + k;
                float p0 = (float)*(bf16*)(smem + (2 * w2)      * SLAB_STRIDE + c * 2);
                float p1 = (float)*(bf16*)(smem + (2 * w2 + 1)  * SLAB_STRIDE + c * 2);
                float p2 = (float)*(bf16*)(smem + (56 + 2 * w2) * SLAB_STRIDE + c * 2);
                float p3 = (float)*(bf16*)(smem + (57 + 2 * w2) * SLAB_STRIDE + c * 2);
                float mx = fmaxf(fmaxf(p0, p1), fmaxf(p2, p3));
                float av = (p0 + p1 + p2 + p3) * 0.25f;
                o_[k] = (bf16)(mx + av);
            }
            *(bf16x2*)(dst + (size_t)c * MPAD + 2 * w2p) = o_;
        }
    }
}

// ---------------------------------------------------------------------------
// k_attn v8: v3's double-buffered staging pipeline for BOTH GEMMs
//            + v4/v5's swapped-operand in-register softmax.
// nt=64, 8 waves: S phase p=wave&3 (16-n frag), h=wave>>2 (448-m half).
// S never touches LDS (scores in 112 regs/lane); P packed once (swizzled b64).
// PV phase identical to v3 (R5, proven 222 us).
// LDS: P_lds [64][1792B] swz (112 KB) + 2x16 KB stage = 144 KB; EX overlays
// the stage region during softmax (idle then).
// ---------------------------------------------------------------------------
#define STG_OFF 114688

__global__ __launch_bounds__(512) void k_attn(
    const bf16* __restrict__ c2n,
    const bf16* __restrict__ c1pT,
    const bf16* __restrict__ c3p,
    const float* __restrict__ x,
    const float* __restrict__ gamma,
    float* __restrict__ out)
{
    const int nb = blockIdx.x, b = blockIdx.y;
    const int n0 = nb * 64;
    const int t = threadIdx.x;
    const int lane = t & 63, wave = t >> 6;
    const int l15 = lane & 15, lg = lane >> 4;
    const int p = wave & 3, h = wave >> 2;

    __shared__ __align__(16) unsigned char smem[147456];
    unsigned char* stg = smem + STG_OFF;
    float* EX = (float*)stg;

    // ---- B-frags: c2 columns for n = n0 + p*16 + l15 (regs, loaded once) ---
    bf16x8 bq[4];
    {
        const bf16* c2b = c2n + ((size_t)b * NPIX + n0 + p * 16 + l15) * CHALF + lg * 8;
        #pragma unroll
        for (int k = 0; k < 4; ++k) bq[k] = *(const bf16x8*)(c2b + k * 32);
    }
    const bf16* c1b = c1pT + (size_t)b * MPAD * CHALF;
    const bf16* c3b = c3p + (size_t)b * CIN * MPAD;

    // ---- S staging addressing: chunk = [64 rows][16 slots x 16B] = 16 KB ---
    // rows 0..31 = h0 (m = mc*32 + r), rows 32..63 = h1 (m = 448 + mc*32 + r)
    // involution: stored slot s holds global c-slot (s&8)|((s&7)^(r&7))
    const int r0 = t >> 4, s0 = t & 15;
    const int cs = (s0 & 8) | ((s0 & 7) ^ (r0 & 7));
    const bf16* sA = c1b + (size_t)r0 * CHALF + cs * 8;
    const bf16* sB = c1b + (size_t)(448 + r0) * CHALF + cs * 8;

    uint4 rXa, rXb, rYa, rYb;
    rXa = *(const uint4*)(sA);
    rXb = *(const uint4*)(sB);
    *(uint4*)(stg + t * 16) = rXa;
    *(uint4*)(stg + 8192 + t * 16) = rXb;
    rYa = *(const uint4*)(sA + 4096);
    rYb = *(const uint4*)(sB + 4096);
    __syncthreads();

    f32x4 sacc[28];
    #pragma unroll
    for (int j = 0; j < 28; ++j) {
        f32x4 z = {0.f, 0.f, 0.f, 0.f};
        sacc[j] = z;
    }

    #pragma unroll
    for (int mc = 0; mc < 14; ++mc) {
        const unsigned char* bufc = stg + (mc & 1) * 16384;
        unsigned char* bufn = stg + ((mc & 1) ^ 1) * 16384;
        if (mc + 1 < 14) {
            if (mc & 1) { *(uint4*)(bufn + t * 16) = rXa; *(uint4*)(bufn + 8192 + t * 16) = rXb; }
            else        { *(uint4*)(bufn + t * 16) = rYa; *(uint4*)(bufn + 8192 + t * 16) = rYb; }
        }
        if (mc + 2 < 14) {
            if (mc & 1) { rYa = *(const uint4*)(sA + (mc + 2) * 4096); rYb = *(const uint4*)(sB + (mc + 2) * 4096); }
            else        { rXa = *(const uint4*)(sA + (mc + 2) * 4096); rXb = *(const uint4*)(sB + (mc + 2) * 4096); }
        }
        #pragma unroll
        for (int sf = 0; sf < 2; ++sf) {
            bf16x8 af[4];
            #pragma unroll
            for (int k = 0; k < 4; ++k)
                af[k] = *(const bf16x8*)(bufc + h * 8192 + (sf * 16 + l15) * 256
                                         + ((lg * 16 + k * 64) ^ ((l15 & 7) << 4)));
            #pragma unroll
            for (int k = 0; k < 4; ++k)
                sacc[mc * 2 + sf] = __builtin_amdgcn_mfma_f32_16x16x32_bf16(
                    af[k], bq[k], sacc[mc * 2 + sf], 0, 0, 0);
        }
        __syncthreads();
    }

    // ---- in-register softmax; lane n = p*16+l15 holds its 448-m half -------
    // valid: h==0 all j; h==1 j<21 (m >= 784 is pad)
    float mx = -1e30f;
    #pragma unroll
    for (int j = 0; j < 28; ++j) {
        if (h == 0 || j < 21)
            mx = fmaxf(mx, fmaxf(fmaxf(sacc[j][0], sacc[j][1]),
                                 fmaxf(sacc[j][2], sacc[j][3])));
    }
    mx = fmaxf(mx, __shfl_xor(mx, 16));
    mx = fmaxf(mx, __shfl_xor(mx, 32));
    if (lane < 16) EX[wave * 16 + l15] = mx;
    __syncthreads();
    mx = fmaxf(mx, EX[(wave ^ 4) * 16 + l15]);

    float s = 0.f;
    #pragma unroll
    for (int j = 0; j < 28; ++j) {
        if (h == 0 || j < 21) {
            #pragma unroll
            for (int r = 0; r < 4; ++r) {
                float e = __expf(sacc[j][r] - mx);
                sacc[j][r] = e;
                s += e;
            }
        }
    }
    s += __shfl_xor(s, 16);
    s += __shfl_xor(s, 32);
    if (lane < 16) EX[128 + wave * 16 + l15] = s;
    __syncthreads();
    s += EX[128 + (wave ^ 4) * 16 + l15];
    const float ri = 1.f / s;

    // ---- pre-issue PV chunk 0 (regs) so HBM latency hides under pack -------
    const int pc = t >> 2, ps = t & 3;
    const bf16* sV  = c3b + (size_t)pc * MPAD + ((ps ^ (pc & 3)) * 8);
    const bf16* sV2 = c3b + (size_t)(pc + 128) * MPAD + ((ps ^ (pc & 3)) * 8);
    rXa = *(const uint4*)(sV);
    rXb = *(const uint4*)(sV2);

    // ---- pack normalized P bf16 -> P_lds (single swizzled b64 per frag) ----
    {
        const int n = p * 16 + l15;
        const unsigned sw = (unsigned)((n & 7) << 4);
        const unsigned rowb = (unsigned)(n * 1792);
        #pragma unroll
        for (int j = 0; j < 28; ++j) {
            bf16x4 w;
            if (h == 0 || j < 21) {
                w = bf16x4{ (bf16)(sacc[j][0] * ri), (bf16)(sacc[j][1] * ri),
                            (bf16)(sacc[j][2] * ri), (bf16)(sacc[j][3] * ri) };
            } else {
                w = bf16x4{ (bf16)0.f, (bf16)0.f, (bf16)0.f, (bf16)0.f };
            }
            unsigned byte = rowb + (unsigned)(h * 896 + j * 32 + lg * 8);
            *(bf16x4*)(smem + (byte ^ sw)) = w;
        }
    }
    __syncthreads();    // P complete; EX dead -> stage region free for PV

    // ---- PV phase: identical to v3 (R5 proven) -----------------------------
    *(uint4*)(stg + t * 16) = rXa;
    *(uint4*)(stg + 8192 + t * 16) = rXb;
    rYa = *(const uint4*)(sV + 32);
    rYb = *(const uint4*)(sV2 + 32);
    __syncthreads();

    const int wn = h, wq = p;
    f32x4 acc2[2][4];
    #pragma unroll
    for (int fn = 0; fn < 2; ++fn)
        #pragma unroll
        for (int fc = 0; fc < 4; ++fc) {
            f32x4 z = {0.f, 0.f, 0.f, 0.f};
            acc2[fn][fc] = z;
        }

    #pragma unroll
    for (int ks = 0; ks < 28; ++ks) {
        const unsigned char* bufc = stg + (ks & 1) * 16384;
        unsigned char* bufn = stg + ((ks & 1) ^ 1) * 16384;
        if (ks + 1 < 28) {
            if (ks & 1) { *(uint4*)(bufn + t * 16) = rXa; *(uint4*)(bufn + 8192 + t * 16) = rXb; }
            else        { *(uint4*)(bufn + t * 16) = rYa; *(uint4*)(bufn + 8192 + t * 16) = rYb; }
        }
        if (ks + 2 < 28) {
            if (ks & 1) { rYa = *(const uint4*)(sV + (ks + 2) * 32); rYb = *(const uint4*)(sV2 + (ks + 2) * 32); }
            else        { rXa = *(const uint4*)(sV + (ks + 2) * 32); rXb = *(const uint4*)(sV2 + (ks + 2) * 32); }
        }
        {
            int nA0 = wn * 32 + l15, nA1 = nA0 + 16;
            int mb = (ks * 32 + lg * 8) * 2;
            bf16x8 af0 = *(const bf16x8*)(smem + ((nA0 * 1792 + mb) ^ ((nA0 & 7) << 4)));
            bf16x8 af1 = *(const bf16x8*)(smem + ((nA1 * 1792 + mb) ^ ((nA1 & 7) << 4)));
            #pragma unroll
            for (int fc = 0; fc < 4; ++fc) {
                int c = wq * 64 + fc * 16 + l15;
                bf16x8 bfr = *(const bf16x8*)(bufc + c * 64 + ((lg ^ (c & 3)) * 16));
                acc2[0][fc] = __builtin_amdgcn_mfma_f32_16x16x32_bf16(af0, bfr, acc2[0][fc], 0, 0, 0);
                acc2[1][fc] = __builtin_amdgcn_mfma_f32_16x16x32_bf16(af1, bfr, acc2[1][fc], 0, 0, 0);
            }
        }
        __syncthreads();
    }

    // ---- epilogue: transpose via LDS, out = g*refined + x ------------------
    float* R = (float*)smem;    // [64][257], P_lds dead
    #pragma unroll
    for (int fn = 0; fn < 2; ++fn)
        #pragma unroll
        for (int fc = 0; fc < 4; ++fc) {
            int c = wq * 64 + fc * 16 + l15;
            #pragma unroll
            for (int r = 0; r < 4; ++r) {
                int n = wn * 32 + fn * 16 + lg * 4 + r;
                R[n * 257 + c] = acc2[fn][fc][r];
            }
        }
    __syncthreads();
    const float g = gamma[0];
    const float* xb = x + (size_t)b * CIN * NPIX + n0;
    float* ob = out + (size_t)b * CIN * NPIX + n0;
    #pragma unroll 4
    for (int i = 0; i < 32; ++i) {
        int idx = t + i * 512;                  // 256 c x 64 n
        int c = idx >> 6, nn = idx & 63;
        size_t off = (size_t)c * NPIX + nn;
        ob[off] = g * R[nn * 257 + c] + xb[off];
    }
}

extern "C" void kernel_launch(void* const* d_in, const int* in_sizes, int n_in,
                              void* d_out, int out_size, void* d_ws, size_t ws_size,
                              hipStream_t stream) {
    const float* x     = (const float*)d_in[0];
    const float* W1    = (const float*)d_in[1];
    const float* W2    = (const float*)d_in[2];
    const float* W3    = (const float*)d_in[3];
    const float* gamma = (const float*)d_in[4];
    float* out = (float*)d_out;

    bf16* ws   = (bf16*)d_ws;
    bf16* Wcat = ws;                                       // 512*256
    bf16* c2n  = Wcat + (size_t)512 * 256;                 // 32*3136*128
    bf16* c1pT = c2n + (size_t)BATCH * NPIX * CHALF;       // 32*896*128
    bf16* c3p  = c1pT + (size_t)BATCH * MPAD * CHALF;      // 32*256*896

    k_cast<<<128, 256, 0, stream>>>(W1, W2, W3, Wcat);
    k_conv<<<dim3(28, BATCH), 512, 0, stream>>>(x, Wcat, c2n, c1pT, c3p);
    k_attn<<<dim3(49, BATCH), 512, 0, stream>>>(c2n, c1pT, c3p, x, gamma, out);
}